// Round 2
// baseline (649.020 us; speedup 1.0000x reference)
//
#include <hip/hip_runtime.h>

typedef short bf16x8 __attribute__((ext_vector_type(8)));
typedef float f32x4  __attribute__((ext_vector_type(4)));

#define CK 64
#define HW 4096
#define MT 64            // m-tile (memory rows per tile)
#define NT 64            // n-strip (query cols per workgroup)
#define KP 72            // padded LDS row length in bf16 elems (144 B, 16B-aligned rows)
#define NTILES (HW / MT) // 64

// round-to-nearest-even fp32 -> bf16 (bit pattern)
static __device__ __forceinline__ unsigned short f2bf(float f) {
    union { float f; unsigned u; } v; v.f = f;
    unsigned r = (v.u + 0x7FFFu + ((v.u >> 16) & 1u)) >> 16;
    return (unsigned short)r;
}

__global__ __launch_bounds__(256, 2)
void amem_fused(const float* __restrict__ Mk, const float* __restrict__ Qk,
                float* __restrict__ out) {
    // transposed bf16 staging: [row][k], k = channel
    __shared__ __attribute__((aligned(16))) unsigned short qk_s[NT][KP];
    __shared__ __attribute__((aligned(16))) unsigned short mk_s[2][MT][KP];

    const int b   = blockIdx.y;
    const int n0  = blockIdx.x * NT;
    const int tid = threadIdx.x;
    const int lane = tid & 63;
    const int wv   = tid >> 6;    // wave 0..3 -> owns cols [wv*16, wv*16+16)
    const int r    = lane & 15;   // fragment row/col
    const int h    = lane >> 4;   // 0..3

    const float* mkb = Mk + (size_t)b * CK * HW;
    const float* qkb = Qk + (size_t)b * CK * HW;

    // ---- stage Qk strip once, scaled by 1/sqrt(CK)=1/8 (exact), transposed ----
    {
        const int c0 = tid >> 4;        // 0..15
        const int n  = (tid & 15) * 4;  // 0..60 step 4
        #pragma unroll
        for (int cc = 0; cc < 4; ++cc) {
            const int c = c0 + cc * 16;
            float4 v = *(const float4*)(qkb + (size_t)c * HW + n0 + n);
            qk_s[n + 0][c] = f2bf(v.x * 0.125f);
            qk_s[n + 1][c] = f2bf(v.y * 0.125f);
            qk_s[n + 2][c] = f2bf(v.z * 0.125f);
            qk_s[n + 3][c] = f2bf(v.w * 0.125f);
        }
    }

    auto stage_mk = [&](int buf, int t) {
        const int c0 = tid >> 4;
        const int m  = (tid & 15) * 4;
        const int m0 = t * MT;
        #pragma unroll
        for (int cc = 0; cc < 4; ++cc) {
            const int c = c0 + cc * 16;
            float4 v = *(const float4*)(mkb + (size_t)c * HW + m0 + m);
            mk_s[buf][m + 0][c] = f2bf(v.x);
            mk_s[buf][m + 1][c] = f2bf(v.y);
            mk_s[buf][m + 2][c] = f2bf(v.z);
            mk_s[buf][m + 3][c] = f2bf(v.w);
        }
    };

    stage_mk(0, 0);
    __syncthreads();

    // loop-invariant B fragments: lane holds B[8h+i][wv*16+r] = qk_s[wv*16+r][8h+i]
    const bf16x8 bf0 = *(const bf16x8*)&qk_s[wv * 16 + r][h * 8];
    const bf16x8 bf1 = *(const bf16x8*)&qk_s[wv * 16 + r][32 + h * 8];

    // ---- PASS 1: per-column sum of exp (no max needed: |affinity| <~ 6) ----
    float ssum = 0.f;
    for (int t = 0; t < NTILES; ++t) {
        const int buf = t & 1;
        if (t + 1 < NTILES) stage_mk(buf ^ 1, t + 1);
        #pragma unroll
        for (int mf = 0; mf < 4; ++mf) {
            f32x4 acc = {0.f, 0.f, 0.f, 0.f};
            bf16x8 a0 = *(const bf16x8*)&mk_s[buf][mf * 16 + r][h * 8];
            bf16x8 a1 = *(const bf16x8*)&mk_s[buf][mf * 16 + r][32 + h * 8];
            acc = __builtin_amdgcn_mfma_f32_16x16x32_bf16(a0, bf0, acc, 0, 0, 0);
            acc = __builtin_amdgcn_mfma_f32_16x16x32_bf16(a1, bf1, acc, 0, 0, 0);
            ssum += __expf(acc[0]) + __expf(acc[1]) + __expf(acc[2]) + __expf(acc[3]);
        }
        __syncthreads();
    }
    // lanes {l, l^16, l^32, l^48} hold disjoint row-partials of the same column
    ssum += __shfl_xor(ssum, 16);
    ssum += __shfl_xor(ssum, 32);
    const float inv = 1.0f / ssum;

    // ---- PASS 2: recompute, normalize, write ----
    stage_mk(0, 0);
    __syncthreads();

    float* outb = out + (size_t)b * HW * HW + n0 + wv * 16 + r; // this lane's column
    for (int t = 0; t < NTILES; ++t) {
        const int buf = t & 1;
        if (t + 1 < NTILES) stage_mk(buf ^ 1, t + 1);
        #pragma unroll
        for (int mf = 0; mf < 4; ++mf) {
            f32x4 acc = {0.f, 0.f, 0.f, 0.f};
            bf16x8 a0 = *(const bf16x8*)&mk_s[buf][mf * 16 + r][h * 8];
            bf16x8 a1 = *(const bf16x8*)&mk_s[buf][mf * 16 + r][32 + h * 8];
            acc = __builtin_amdgcn_mfma_f32_16x16x32_bf16(a0, bf0, acc, 0, 0, 0);
            acc = __builtin_amdgcn_mfma_f32_16x16x32_bf16(a1, bf1, acc, 0, 0, 0);
            const int mbase = t * MT + mf * 16 + h * 4; // D row = 4h + reg
            #pragma unroll
            for (int i = 0; i < 4; ++i)
                outb[(size_t)(mbase + i) * HW] = __expf(acc[i]) * inv;
        }
        __syncthreads();
    }
}

extern "C" void kernel_launch(void* const* d_in, const int* in_sizes, int n_in,
                              void* d_out, int out_size, void* d_ws, size_t ws_size,
                              hipStream_t stream) {
    (void)n_in; (void)out_size; (void)d_ws; (void)ws_size;
    const float* Mk = (const float*)d_in[0];
    const float* Qk = (const float*)d_in[1];
    float* out = (float*)d_out;
    const int B = in_sizes[0] / (CK * HW); // 8
    dim3 grid(HW / NT, B);
    amem_fused<<<grid, 256, 0, stream>>>(Mk, Qk, out);
}

// Round 3
// 583.897 us; speedup vs baseline: 1.1115x; 1.1115x over previous
//
#include <hip/hip_runtime.h>

typedef short bf16x8 __attribute__((ext_vector_type(8)));
typedef float f32x4  __attribute__((ext_vector_type(4)));

#define CK 64
#define HW 4096
#define MT 64                  // m-tile rows
#define NT 64                  // query cols per workgroup
#define NTILES (HW / MT)       // 64
#define ROW_BYTES (CK * 2)     // 128 B per bf16 row
#define TILE_BYTES (MT * ROW_BYTES) // 8192

// round-to-nearest-even fp32 -> bf16 (bit pattern)
static __device__ __forceinline__ unsigned short f2bf(float f) {
    union { float f; unsigned u; } v; v.f = f;
    return (unsigned short)((v.u + 0x7FFFu + ((v.u >> 16) & 1u)) >> 16);
}

typedef const __attribute__((address_space(1))) unsigned int* gas_t;
typedef __attribute__((address_space(3))) unsigned int* las_t;
static __device__ __forceinline__ void load_lds16(const void* g, void* l) {
    __builtin_amdgcn_global_load_lds((gas_t)g, (las_t)l, 16, 0, 0);
}

// ---- Kernel A: [c][m] f32 -> [m][c] bf16 rows, XOR-swizzled (byte ^= (m&7)<<4).
// Qk additionally scaled by 1/sqrt(CK) = 1/8 (exact in bf16).
__global__ __launch_bounds__(256)
void amem_prep(const float* __restrict__ Mk, const float* __restrict__ Qk,
               unsigned short* __restrict__ Mt, unsigned short* __restrict__ Qt) {
    const int b  = blockIdx.y;
    const int m0 = blockIdx.x * 64;
    const int tid = threadIdx.x;
    const int c4 = (tid >> 4) * 4;   // 4 consecutive channels
    const int m4 = (tid & 15) * 4;   // 4 consecutive m
    #pragma unroll
    for (int s = 0; s < 2; ++s) {
        const float* src = (s == 0 ? Mk : Qk) + (size_t)b * CK * HW;
        char* dst = (char*)((s == 0 ? Mt : Qt) + (size_t)b * CK * HW);
        const float sc = (s == 0) ? 1.0f : 0.125f;
        float4 v[4];
        #pragma unroll
        for (int je = 0; je < 4; ++je)
            v[je] = *(const float4*)(src + (size_t)(c4 + je) * HW + m0 + m4);
        #pragma unroll
        for (int j = 0; j < 4; ++j) {
            const float x0 = ((const float*)&v[0])[j] * sc;
            const float x1 = ((const float*)&v[1])[j] * sc;
            const float x2 = ((const float*)&v[2])[j] * sc;
            const float x3 = ((const float*)&v[3])[j] * sc;
            const unsigned lo = f2bf(x0) | ((unsigned)f2bf(x1) << 16);
            const unsigned hi = f2bf(x2) | ((unsigned)f2bf(x3) << 16);
            const int m = m0 + m4 + j;
            const size_t byte = (size_t)m * ROW_BYTES
                              + (((unsigned)(c4 * 2)) ^ (unsigned)((m & 7) << 4));
            *(uint2*)(dst + byte) = make_uint2(lo, hi);
        }
    }
}

// ---- Kernel B: fused Mk^T·Qk + softmax(axis=memory), recompute two-pass.
__global__ __launch_bounds__(256, 2)
void amem_main(const unsigned short* __restrict__ Mt, const unsigned short* __restrict__ Qt,
               float* __restrict__ out) {
    __shared__ __attribute__((aligned(16))) unsigned short qk_s[NT * CK];     // 8 KB
    __shared__ __attribute__((aligned(16))) unsigned short mk_s[2][MT * CK];  // 2x8 KB

    const int b    = blockIdx.y;
    const int n0   = blockIdx.x * NT;
    const int tid  = threadIdx.x;
    const int lane = tid & 63;
    const int wv   = tid >> 6;     // wave owns cols [wv*16, wv*16+16)
    const int r    = lane & 15;
    const int h    = lane >> 4;

    const char* mtb = (const char*)(Mt + (size_t)b * CK * HW); // rows m*128B, swizzled
    const char* qtb = (const char*)(Qt + (size_t)b * CK * HW);

    auto stagem = [&](int buf, int t) {
        #pragma unroll
        for (int i = 0; i < 2; ++i) {
            const int o = wv * 2048 + i * 1024;
            load_lds16(mtb + (size_t)t * TILE_BYTES + o + lane * 16,
                       (char*)mk_s[buf] + o);  // LDS dest wave-uniform; HW adds lane*16
        }
    };
    // stage Qk strip + Mk tile 0
    #pragma unroll
    for (int i = 0; i < 2; ++i) {
        const int o = wv * 2048 + i * 1024;
        load_lds16(qtb + (size_t)n0 * ROW_BYTES + o + lane * 16, (char*)qk_s + o);
    }
    stagem(0, 0);
    __syncthreads();

    // swizzled intra-row offsets for this lane's fragments (16B aligned)
    const int xr = (r & 7) << 4;
    const int o0 = (h * 16) ^ xr;        // k = 0..31 half
    const int o1 = (64 + h * 16) ^ xr;   // k = 32..63 half

    // loop-invariant B fragments: B[k][col=wv*16+r] = Qt[n0+wv*16+r][k]
    const char* qb = (const char*)qk_s + (wv * 16 + r) * ROW_BYTES;
    const bf16x8 bf0 = *(const bf16x8*)(qb + o0);
    const bf16x8 bf1 = *(const bf16x8*)(qb + o1);

    // ---- PASS 1: per-column sum of exp (no max: affinity ~ N(0,1)) ----
    float ssum = 0.f;
    for (int t = 0; t < NTILES; ++t) {
        const int buf = t & 1;
        if (t + 1 < NTILES) stagem(buf ^ 1, t + 1);
        #pragma unroll
        for (int mf = 0; mf < 4; ++mf) {
            const char* mb = (const char*)mk_s[buf] + (mf * 16 + r) * ROW_BYTES;
            f32x4 acc = {0.f, 0.f, 0.f, 0.f};
            acc = __builtin_amdgcn_mfma_f32_16x16x32_bf16(*(const bf16x8*)(mb + o0), bf0, acc, 0, 0, 0);
            acc = __builtin_amdgcn_mfma_f32_16x16x32_bf16(*(const bf16x8*)(mb + o1), bf1, acc, 0, 0, 0);
            ssum += __expf(acc[0]) + __expf(acc[1]) + __expf(acc[2]) + __expf(acc[3]);
        }
        __syncthreads();
    }
    // lanes {l, l^16, l^32, l^48} hold disjoint row-blocks of the same column
    ssum += __shfl_xor(ssum, 16);
    ssum += __shfl_xor(ssum, 32);
    const float inv = 1.0f / ssum;

    // ---- PASS 2: recompute, normalize, write ----
    stagem(0, 0);
    __syncthreads();
    float* outb = out + (size_t)b * HW * HW + n0 + wv * 16 + r; // this lane's column
    for (int t = 0; t < NTILES; ++t) {
        const int buf = t & 1;
        if (t + 1 < NTILES) stagem(buf ^ 1, t + 1);
        #pragma unroll
        for (int mf = 0; mf < 4; ++mf) {
            const char* mb = (const char*)mk_s[buf] + (mf * 16 + r) * ROW_BYTES;
            f32x4 acc = {0.f, 0.f, 0.f, 0.f};
            acc = __builtin_amdgcn_mfma_f32_16x16x32_bf16(*(const bf16x8*)(mb + o0), bf0, acc, 0, 0, 0);
            acc = __builtin_amdgcn_mfma_f32_16x16x32_bf16(*(const bf16x8*)(mb + o1), bf1, acc, 0, 0, 0);
            const int mbase = t * MT + mf * 16 + h * 4; // D row = 4h + reg
            #pragma unroll
            for (int i = 0; i < 4; ++i)
                outb[(size_t)(mbase + i) * HW] = __expf(acc[i]) * inv;
        }
        __syncthreads();
    }
}

// ---- Fallback (R2 kernel, passes at 649 us) if ws is too small ----
#define KP 72
__global__ __launch_bounds__(256, 2)
void amem_fused(const float* __restrict__ Mk, const float* __restrict__ Qk,
                float* __restrict__ out) {
    __shared__ __attribute__((aligned(16))) unsigned short qk_f[NT][KP];
    __shared__ __attribute__((aligned(16))) unsigned short mk_f[2][MT][KP];
    const int b = blockIdx.y, n0 = blockIdx.x * NT, tid = threadIdx.x;
    const int lane = tid & 63, wv = tid >> 6, r = lane & 15, h = lane >> 4;
    const float* mkb = Mk + (size_t)b * CK * HW;
    const float* qkb = Qk + (size_t)b * CK * HW;
    {
        const int c0 = tid >> 4, n = (tid & 15) * 4;
        #pragma unroll
        for (int cc = 0; cc < 4; ++cc) {
            const int c = c0 + cc * 16;
            float4 v = *(const float4*)(qkb + (size_t)c * HW + n0 + n);
            qk_f[n + 0][c] = f2bf(v.x * 0.125f); qk_f[n + 1][c] = f2bf(v.y * 0.125f);
            qk_f[n + 2][c] = f2bf(v.z * 0.125f); qk_f[n + 3][c] = f2bf(v.w * 0.125f);
        }
    }
    auto stage_mk = [&](int buf, int t) {
        const int c0 = tid >> 4, m = (tid & 15) * 4, m0 = t * MT;
        #pragma unroll
        for (int cc = 0; cc < 4; ++cc) {
            const int c = c0 + cc * 16;
            float4 v = *(const float4*)(mkb + (size_t)c * HW + m0 + m);
            mk_f[buf][m + 0][c] = f2bf(v.x); mk_f[buf][m + 1][c] = f2bf(v.y);
            mk_f[buf][m + 2][c] = f2bf(v.z); mk_f[buf][m + 3][c] = f2bf(v.w);
        }
    };
    stage_mk(0, 0);
    __syncthreads();
    const bf16x8 bf0 = *(const bf16x8*)&qk_f[wv * 16 + r][h * 8];
    const bf16x8 bf1 = *(const bf16x8*)&qk_f[wv * 16 + r][32 + h * 8];
    float ssum = 0.f;
    for (int t = 0; t < NTILES; ++t) {
        const int buf = t & 1;
        if (t + 1 < NTILES) stage_mk(buf ^ 1, t + 1);
        #pragma unroll
        for (int mf = 0; mf < 4; ++mf) {
            f32x4 acc = {0.f, 0.f, 0.f, 0.f};
            acc = __builtin_amdgcn_mfma_f32_16x16x32_bf16(*(const bf16x8*)&mk_f[buf][mf * 16 + r][h * 8], bf0, acc, 0, 0, 0);
            acc = __builtin_amdgcn_mfma_f32_16x16x32_bf16(*(const bf16x8*)&mk_f[buf][mf * 16 + r][32 + h * 8], bf1, acc, 0, 0, 0);
            ssum += __expf(acc[0]) + __expf(acc[1]) + __expf(acc[2]) + __expf(acc[3]);
        }
        __syncthreads();
    }
    ssum += __shfl_xor(ssum, 16); ssum += __shfl_xor(ssum, 32);
    const float inv = 1.0f / ssum;
    stage_mk(0, 0);
    __syncthreads();
    float* outb = out + (size_t)b * HW * HW + n0 + wv * 16 + r;
    for (int t = 0; t < NTILES; ++t) {
        const int buf = t & 1;
        if (t + 1 < NTILES) stage_mk(buf ^ 1, t + 1);
        #pragma unroll
        for (int mf = 0; mf < 4; ++mf) {
            f32x4 acc = {0.f, 0.f, 0.f, 0.f};
            acc = __builtin_amdgcn_mfma_f32_16x16x32_bf16(*(const bf16x8*)&mk_f[buf][mf * 16 + r][h * 8], bf0, acc, 0, 0, 0);
            acc = __builtin_amdgcn_mfma_f32_16x16x32_bf16(*(const bf16x8*)&mk_f[buf][mf * 16 + r][32 + h * 8], bf1, acc, 0, 0, 0);
            const int mbase = t * MT + mf * 16 + h * 4;
            #pragma unroll
            for (int i = 0; i < 4; ++i)
                outb[(size_t)(mbase + i) * HW] = __expf(acc[i]) * inv;
        }
        __syncthreads();
    }
}

extern "C" void kernel_launch(void* const* d_in, const int* in_sizes, int n_in,
                              void* d_out, int out_size, void* d_ws, size_t ws_size,
                              hipStream_t stream) {
    (void)n_in; (void)out_size;
    const float* Mk = (const float*)d_in[0];
    const float* Qk = (const float*)d_in[1];
    float* out = (float*)d_out;
    const int B = in_sizes[0] / (CK * HW); // 8
    const size_t need = 2 * (size_t)B * CK * HW * 2; // Mt + Qt, bf16
    if (ws_size >= need) {
        unsigned short* Mt = (unsigned short*)d_ws;
        unsigned short* Qt = Mt + (size_t)B * CK * HW;
        dim3 grid(HW / 64, B);
        amem_prep<<<grid, 256, 0, stream>>>(Mk, Qk, Mt, Qt);
        amem_main<<<dim3(HW / NT, B), 256, 0, stream>>>(Mt, Qt, out);
    } else {
        amem_fused<<<dim3(HW / NT, B), 256, 0, stream>>>(Mk, Qk, out);
    }
}

// Round 5
// 579.407 us; speedup vs baseline: 1.1201x; 1.0077x over previous
//
#include <hip/hip_runtime.h>

typedef short bf16x8 __attribute__((ext_vector_type(8)));
typedef float f32x4  __attribute__((ext_vector_type(4)));

#define CK 64
#define HW 4096
#define MT 64                  // m-tile rows
#define NT 64                  // query cols per workgroup
#define NTILES (HW / MT)       // 64
#define ROW_BYTES (CK * 2)     // 128 B per bf16 row
#define TILE_BYTES (MT * ROW_BYTES) // 8192

#define WAITVM(N)  asm volatile("s_waitcnt vmcnt(" #N ")" ::: "memory")
#define WAITLGKM() asm volatile("s_waitcnt lgkmcnt(0)" ::: "memory")
#define SBAR()     do { __builtin_amdgcn_s_barrier(); __builtin_amdgcn_sched_barrier(0); } while (0)

// round-to-nearest-even fp32 -> bf16 (bit pattern)
static __device__ __forceinline__ unsigned short f2bf(float f) {
    union { float f; unsigned u; } v; v.f = f;
    return (unsigned short)((v.u + 0x7FFFu + ((v.u >> 16) & 1u)) >> 16);
}

typedef const __attribute__((address_space(1))) unsigned int* gas_t;
typedef __attribute__((address_space(3))) unsigned int* las_t;
static __device__ __forceinline__ void load_lds16(const void* g, void* l) {
    __builtin_amdgcn_global_load_lds((gas_t)g, (las_t)l, 16, 0, 0);
}

// ---- Kernel A: [c][m] f32 -> [m][c] bf16 rows, XOR-swizzled (byte ^= (m&7)<<4).
// Qk additionally scaled by 1/sqrt(CK) = 1/8 (exact in bf16).
__global__ __launch_bounds__(256)
void amem_prep(const float* __restrict__ Mk, const float* __restrict__ Qk,
               unsigned short* __restrict__ Mt, unsigned short* __restrict__ Qt) {
    const int b  = blockIdx.y;
    const int m0 = blockIdx.x * 64;
    const int tid = threadIdx.x;
    const int c4 = (tid >> 4) * 4;   // 4 consecutive channels
    const int m4 = (tid & 15) * 4;   // 4 consecutive m
    #pragma unroll
    for (int s = 0; s < 2; ++s) {
        const float* src = (s == 0 ? Mk : Qk) + (size_t)b * CK * HW;
        char* dst = (char*)((s == 0 ? Mt : Qt) + (size_t)b * CK * HW);
        const float sc = (s == 0) ? 1.0f : 0.125f;
        float4 v[4];
        #pragma unroll
        for (int je = 0; je < 4; ++je)
            v[je] = *(const float4*)(src + (size_t)(c4 + je) * HW + m0 + m4);
        #pragma unroll
        for (int j = 0; j < 4; ++j) {
            const float x0 = ((const float*)&v[0])[j] * sc;
            const float x1 = ((const float*)&v[1])[j] * sc;
            const float x2 = ((const float*)&v[2])[j] * sc;
            const float x3 = ((const float*)&v[3])[j] * sc;
            const unsigned lo = f2bf(x0) | ((unsigned)f2bf(x1) << 16);
            const unsigned hi = f2bf(x2) | ((unsigned)f2bf(x3) << 16);
            const int m = m0 + m4 + j;
            const size_t byte = (size_t)m * ROW_BYTES
                              + (((unsigned)(c4 * 2)) ^ (unsigned)((m & 7) << 4));
            *(uint2*)(dst + byte) = make_uint2(lo, hi);
        }
    }
}

// ---- Kernel B: fused Mk^T·Qk + softmax(axis=memory), recompute two-pass.
// 3-buffer prefetch-2 pipeline, counted vmcnt, raw s_barrier (T3+T4).
__global__ __launch_bounds__(256, 2)
void amem_main(const unsigned short* __restrict__ Mt, const unsigned short* __restrict__ Qt,
               float* __restrict__ out) {
    __shared__ __attribute__((aligned(16))) unsigned short qk_s[NT * CK];     // 8 KB
    __shared__ __attribute__((aligned(16))) unsigned short mk_s[3][MT * CK];  // 3x8 KB

    const int b    = blockIdx.y;
    const int n0   = blockIdx.x * NT;
    const int tid  = threadIdx.x;
    const int lane = tid & 63;
    const int wv   = tid >> 6;     // wave owns cols [wv*16, wv*16+16)
    const int r    = lane & 15;
    const int h    = lane >> 4;

    const char* mtb = (const char*)(Mt + (size_t)b * CK * HW); // rows m*128B, swizzled
    const char* qtb = (const char*)(Qt + (size_t)b * CK * HW);

    auto stagem = [&](int buf, int t) {
        #pragma unroll
        for (int i = 0; i < 2; ++i) {
            const int o = wv * 2048 + i * 1024;
            load_lds16(mtb + (size_t)t * TILE_BYTES + o + lane * 16,
                       (char*)mk_s[buf] + o);  // LDS dest wave-uniform; HW adds lane*16
        }
    };

    // ---- prologue: qk strip + Mk tiles 0,1 ----
    #pragma unroll
    for (int i = 0; i < 2; ++i) {
        const int o = wv * 2048 + i * 1024;
        load_lds16(qtb + (size_t)n0 * ROW_BYTES + o + lane * 16, (char*)qk_s + o);
    }
    stagem(0, 0);
    stagem(1, 1);
    WAITVM(2);   // qk + L(0) done; L(1) may remain in flight
    SBAR();

    // swizzled intra-row offsets for this lane's fragments (16B aligned)
    const int xr = (r & 7) << 4;
    const int o0 = (h * 16) ^ xr;        // k = 0..31 half
    const int o1 = (64 + h * 16) ^ xr;   // k = 32..63 half

    // loop-invariant B fragments: B[k][col=wv*16+r] = Qt[n0+wv*16+r][k]
    const char* qb = (const char*)qk_s + (wv * 16 + r) * ROW_BYTES;
    const bf16x8 bf0 = *(const bf16x8*)(qb + o0);
    const bf16x8 bf1 = *(const bf16x8*)(qb + o1);

    // ---- PASS 1: per-column sum of exp (no max: affinity ~ N(0,1)) ----
    float ssum = 0.f;
    for (int t = 0; t < NTILES; ++t) {
        const int buf = t % 3;
        if (t + 2 < NTILES) stagem((t + 2) % 3, t + 2);
        #pragma unroll
        for (int mf = 0; mf < 4; ++mf) {
            const char* mb = (const char*)mk_s[buf] + (mf * 16 + r) * ROW_BYTES;
            f32x4 acc = {0.f, 0.f, 0.f, 0.f};
            acc = __builtin_amdgcn_mfma_f32_16x16x32_bf16(*(const bf16x8*)(mb + o0), bf0, acc, 0, 0, 0);
            acc = __builtin_amdgcn_mfma_f32_16x16x32_bf16(*(const bf16x8*)(mb + o1), bf1, acc, 0, 0, 0);
            ssum += __expf(acc[0]) + __expf(acc[1]) + __expf(acc[2]) + __expf(acc[3]);
        }
        // end-of-iter: guarantee L(t+1) landed; never wait the newest prefetch
        if (t + 2 < NTILES)      { WAITVM(2); }
        else if (t + 1 < NTILES) { WAITVM(0); }   // tail: only L(63) outstanding
        WAITLGKM();
        SBAR();
    }
    // lanes {l, l^16, l^32, l^48} hold disjoint row-blocks of the same column
    ssum += __shfl_xor(ssum, 16);
    ssum += __shfl_xor(ssum, 32);
    const float inv = 1.0f / ssum;

    // ---- PASS 2: recompute, normalize, write ----
    stagem(0, 0);
    stagem(1, 1);
    WAITVM(2);   // L(0) done; L(1) in flight
    WAITLGKM();
    SBAR();
    float* outb = out + (size_t)b * HW * HW + n0 + wv * 16 + r; // this lane's column
    for (int t = 0; t < NTILES; ++t) {
        const int buf = t % 3;
        if (t + 2 < NTILES) stagem((t + 2) % 3, t + 2);
        #pragma unroll
        for (int mf = 0; mf < 4; ++mf) {
            const char* mb = (const char*)mk_s[buf] + (mf * 16 + r) * ROW_BYTES;
            f32x4 acc = {0.f, 0.f, 0.f, 0.f};
            acc = __builtin_amdgcn_mfma_f32_16x16x32_bf16(*(const bf16x8*)(mb + o0), bf0, acc, 0, 0, 0);
            acc = __builtin_amdgcn_mfma_f32_16x16x32_bf16(*(const bf16x8*)(mb + o1), bf1, acc, 0, 0, 0);
            const int mbase = t * MT + mf * 16 + h * 4; // D row = 4h + reg
            #pragma unroll
            for (int i = 0; i < 4; ++i)
                outb[(size_t)(mbase + i) * HW] = __expf(acc[i]) * inv;
        }
        // counted waits: stores (16/iter) are allowed to stay in flight.
        // in-order vmcnt retirement guarantees L(t+1) is retired once the
        // allowed-residue (newest ops) excludes it.
        if (t == 0)              { WAITVM(18); }  // newest 18 = L(2)2 + S(0)16
        else if (t + 2 < NTILES) { WAITVM(34); }  // newest 34 = S(t)16+L(t+2)2+S(t-1)16
        else if (t + 1 < NTILES) { WAITVM(32); }  // t=62: newest 32 = S(62)16+S(61)16
        WAITLGKM();
        SBAR();
    }
}

// ---- Fallback (R2 kernel) if ws is too small ----
#define KP 72
__global__ __launch_bounds__(256, 2)
void amem_fused(const float* __restrict__ Mk, const float* __restrict__ Qk,
                float* __restrict__ out) {
    __shared__ __attribute__((aligned(16))) unsigned short qk_f[NT][KP];
    __shared__ __attribute__((aligned(16))) unsigned short mk_f[2][MT][KP];
    const int b = blockIdx.y, n0 = blockIdx.x * NT, tid = threadIdx.x;
    const int lane = tid & 63, wv = tid >> 6, r = lane & 15, h = lane >> 4;
    const float* mkb = Mk + (size_t)b * CK * HW;
    const float* qkb = Qk + (size_t)b * CK * HW;
    {
        const int c0 = tid >> 4, n = (tid & 15) * 4;
        #pragma unroll
        for (int cc = 0; cc < 4; ++cc) {
            const int c = c0 + cc * 16;
            float4 v = *(const float4*)(qkb + (size_t)c * HW + n0 + n);
            qk_f[n + 0][c] = f2bf(v.x * 0.125f); qk_f[n + 1][c] = f2bf(v.y * 0.125f);
            qk_f[n + 2][c] = f2bf(v.z * 0.125f); qk_f[n + 3][c] = f2bf(v.w * 0.125f);
        }
    }
    auto stage_mk = [&](int buf, int t) {
        const int c0 = tid >> 4, m = (tid & 15) * 4, m0 = t * MT;
        #pragma unroll
        for (int cc = 0; cc < 4; ++cc) {
            const int c = c0 + cc * 16;
            float4 v = *(const float4*)(mkb + (size_t)c * HW + m0 + m);
            mk_f[buf][m + 0][c] = f2bf(v.x); mk_f[buf][m + 1][c] = f2bf(v.y);
            mk_f[buf][m + 2][c] = f2bf(v.z); mk_f[buf][m + 3][c] = f2bf(v.w);
        }
    };
    stage_mk(0, 0);
    __syncthreads();
    const bf16x8 bf0 = *(const bf16x8*)&qk_f[wv * 16 + r][h * 8];
    const bf16x8 bf1 = *(const bf16x8*)&qk_f[wv * 16 + r][32 + h * 8];
    float ssum = 0.f;
    for (int t = 0; t < NTILES; ++t) {
        const int buf = t & 1;
        if (t + 1 < NTILES) stage_mk(buf ^ 1, t + 1);
        #pragma unroll
        for (int mf = 0; mf < 4; ++mf) {
            f32x4 acc = {0.f, 0.f, 0.f, 0.f};
            acc = __builtin_amdgcn_mfma_f32_16x16x32_bf16(*(const bf16x8*)&mk_f[buf][mf * 16 + r][h * 8], bf0, acc, 0, 0, 0);
            acc = __builtin_amdgcn_mfma_f32_16x16x32_bf16(*(const bf16x8*)&mk_f[buf][mf * 16 + r][32 + h * 8], bf1, acc, 0, 0, 0);
            ssum += __expf(acc[0]) + __expf(acc[1]) + __expf(acc[2]) + __expf(acc[3]);
        }
        __syncthreads();
    }
    ssum += __shfl_xor(ssum, 16); ssum += __shfl_xor(ssum, 32);
    const float inv = 1.0f / ssum;
    stage_mk(0, 0);
    __syncthreads();
    float* outb = out + (size_t)b * HW * HW + n0 + wv * 16 + r;
    for (int t = 0; t < NTILES; ++t) {
        const int buf = t & 1;
        if (t + 1 < NTILES) stage_mk(buf ^ 1, t + 1);
        #pragma unroll
        for (int mf = 0; mf < 4; ++mf) {
            f32x4 acc = {0.f, 0.f, 0.f, 0.f};
            acc = __builtin_amdgcn_mfma_f32_16x16x32_bf16(*(const bf16x8*)&mk_f[buf][mf * 16 + r][h * 8], bf0, acc, 0, 0, 0);
            acc = __builtin_amdgcn_mfma_f32_16x16x32_bf16(*(const bf16x8*)&mk_f[buf][mf * 16 + r][32 + h * 8], bf1, acc, 0, 0, 0);
            const int mbase = t * MT + mf * 16 + h * 4;
            #pragma unroll
            for (int i = 0; i < 4; ++i)
                outb[(size_t)(mbase + i) * HW] = __expf(acc[i]) * inv;
        }
        __syncthreads();
    }
}

extern "C" void kernel_launch(void* const* d_in, const int* in_sizes, int n_in,
                              void* d_out, int out_size, void* d_ws, size_t ws_size,
                              hipStream_t stream) {
    (void)n_in; (void)out_size;
    const float* Mk = (const float*)d_in[0];
    const float* Qk = (const float*)d_in[1];
    float* out = (float*)d_out;
    const int B = in_sizes[0] / (CK * HW); // 8
    const size_t need = 2 * (size_t)B * CK * HW * 2; // Mt + Qt, bf16
    if (ws_size >= need) {
        unsigned short* Mt = (unsigned short*)d_ws;
        unsigned short* Qt = Mt + (size_t)B * CK * HW;
        amem_prep<<<dim3(HW / 64, B), 256, 0, stream>>>(Mk, Qk, Mt, Qt);
        amem_main<<<dim3(HW / NT, B), 256, 0, stream>>>(Mt, Qt, out);
    } else {
        amem_fused<<<dim3(HW / NT, B), 256, 0, stream>>>(Mk, Qk, out);
    }
}